// Round 14
// baseline (140.454 us; speedup 1.0000x reference)
//
#include <hip/hip_runtime.h>
#include <hip/hip_bf16.h>
#include <cmath>

#define N_NODES 50000
#define N_EDGES 800000
#define CAP 64                                /* per-node cap; Poisson(16) tail @64 ~1e-19 */

#define NBINS 196                             /* bin = dst >> 8 (256 nodes/bin) */
#define BIN_CAP 8192                          /* expected ~4096/bin */
#define CUR_PAD 32                            /* 1 cache line per bin cursor */

#define P1_EPT 16                             /* edges per thread (1024-thr blocks) */
#define P1_EPB (1024 * P1_EPT)                /* 16384 */
#define P1_BLOCKS ((N_EDGES + P1_EPB - 1) / P1_EPB)  /* 49 */

#define HROW 40                               /* hb row: 32 feat + 4 el(bf16) + 4 pad, 80 B */

#define ELR_BLOCKS 196                        /* 3125 tiles / 16 waves */
#define WC_BLOCKS 30                          /* 30720 items / 1024 */
#define NB_ELR (P1_BLOCKS)                    /* 49 */
#define NB_WC  (NB_ELR + ELR_BLOCKS)          /* 245 */
#define NB_WGB (NB_WC + WC_BLOCKS)            /* 275 */
#define PREP_TOTAL (NB_WGB + 1)               /* 276 */

#define AGGR_BLOCKS (N_NODES / 16)            /* 3125 */

typedef __attribute__((ext_vector_type(8))) short bf16x8;
typedef __attribute__((ext_vector_type(4))) float f32x4;

__device__ inline short bfbits(float x) {
    __hip_bfloat16 t = __float2bfloat16(x);
    return *reinterpret_cast<short*>(&t);
}
__device__ inline unsigned short bfu16(float x) {
    __hip_bfloat16 t = __float2bfloat16(x);
    return *reinterpret_cast<unsigned short*>(&t);
}

// ---------------------------------------------------------------------------
// K1 (fused bin-partition + prep), 1024 threads/block.
// R14: hb role FUSED into elr role — the MFMA A-fragment (row m_base+li,
// cols quad*8..+7, bf16x8) IS the hb sector-1 data; store it directly.
// Saves a full 6.4 MB h re-read + 98 blocks.
// [0,49): partition (R10-proven bin pipeline).
// [49,245): elr: hb sector 1 (feats) + el bf16 (sector 2) + er f32.
// [245,275): Wc (GRU GEMM B). [275]: Wgb (projection B fragments).
// ---------------------------------------------------------------------------
__global__ __launch_bounds__(1024) void k_part_prep(
        const int* __restrict__ src, const int* __restrict__ dst,
        int* __restrict__ bin_cursor, unsigned* __restrict__ bin_buf,
        const float* __restrict__ h, const float* __restrict__ Wg,
        const float* __restrict__ al, const float* __restrict__ ar,
        const float* __restrict__ Wih, const float* __restrict__ Whh,
        unsigned short* __restrict__ hb, float* __restrict__ er,
        __hip_bfloat16* __restrict__ Wc, __hip_bfloat16* __restrict__ Wgb) {
    const int t = threadIdx.x;
    __shared__ union {
        struct {
            int bcnt[256], bofs[256], cur[256], gbase[256];
            int wt4[4];
            unsigned stage[P1_EPB];           // 64 KB
        } part;                               // ~68.1 KB
        __hip_bfloat16 vlr[16][32];           // 1 KB
    } sm;

    if (blockIdx.x < P1_BLOCKS) {
        // ---- partition role (R10-proven) ----
        int* bcnt = sm.part.bcnt; int* bofs = sm.part.bofs;
        int* cur = sm.part.cur;   int* gbase = sm.part.gbase;
        int* wt4 = sm.part.wt4;   unsigned* stage = sm.part.stage;
        if (t < 256) bcnt[t] = 0;
        __syncthreads();
        int bn[P1_EPT];
        unsigned pk[P1_EPT];
        const int ebase = blockIdx.x * P1_EPB + t * P1_EPT;  // 800000%16==0
        if (ebase < N_EDGES) {
            int dd[P1_EPT], ss[P1_EPT];
#pragma unroll
            for (int q = 0; q < P1_EPT / 4; ++q) {
                *(int4*)(dd + q * 4) = *(const int4*)(dst + ebase + q * 4);
                *(int4*)(ss + q * 4) = *(const int4*)(src + ebase + q * 4);
            }
#pragma unroll
            for (int q = 0; q < P1_EPT; ++q) {
                bn[q] = dd[q] >> 8;
                pk[q] = (unsigned)ss[q] | ((unsigned)dd[q] << 16);
                atomicAdd(&bcnt[bn[q]], 1);
            }
        } else {
#pragma unroll
            for (int q = 0; q < P1_EPT; ++q) bn[q] = -1;
        }
        __syncthreads();
        int x = 0, vv = 0;
        if (t < 256) {
            vv = bcnt[t];
            x = vv;
            const int lane = t & 63;
#pragma unroll
            for (int m = 1; m < 64; m <<= 1) {
                const int y = __shfl_up(x, m, 64);
                if (lane >= m) x += y;
            }
            if (lane == 63) wt4[t >> 6] = x;
        }
        __syncthreads();
        if (t < 256) {
            const int wave4 = t >> 6;
            int wb = 0;
#pragma unroll
            for (int i = 0; i < 4; ++i) if (i < wave4) wb += wt4[i];
            const int off = wb + x - vv;
            bofs[t] = off;
            cur[t] = off;
            gbase[t] = (vv > 0) ? atomicAdd(&bin_cursor[t * CUR_PAD], vv) : 0;
        }
        __syncthreads();
        if (bn[0] >= 0) {
#pragma unroll
            for (int q = 0; q < P1_EPT; ++q)
                stage[atomicAdd(&cur[bn[q]], 1)] = pk[q];
        }
        __syncthreads();
        // coalesced cooperative flush (block-owned contiguous ranges)
        const int tot = wt4[0] + wt4[1] + wt4[2] + wt4[3];
        for (int i = t; i < tot; i += 1024) {
            const unsigned e = stage[i];
            const int b = e >> 24;                 // dst>>8 (dst<2^16)
            const int gi = gbase[b] + (i - bofs[b]);
            if (gi < BIN_CAP) bin_buf[(size_t)b * BIN_CAP + gi] = e;
        }
        return;
    }
    if (blockIdx.x < NB_WC) {
        // ---- elr role (hb fused): feats bf16 + el bf16 + er f32 ----
        if (t < 512) {
            const int col = t >> 5, k = t & 31;
            float v = 0.f;
            if (col < 8) {
                const int hd = col & 3;
                const float* a = (col < 4) ? (al + hd * 32) : (ar + hd * 32);
                const float* w = Wg + k * 128 + hd * 32;
#pragma unroll
                for (int f = 0; f < 32; ++f) v = fmaf(w[f], a[f], v);
            }
            sm.vlr[col][k] = __float2bfloat16(v);
        }
        __syncthreads();
        const int wave = t >> 6, lane = t & 63;
        const int li = lane & 15, quad = lane >> 4;
        const int mt = (blockIdx.x - NB_ELR) * 16 + wave;
        if (mt >= AGGR_BLOCKS) return;
        const int m_base = mt * 16;
        bf16x8 a;
        {
            const float4* hp = (const float4*)(h + (size_t)(m_base + li) * 32 + quad * 8);
            const float4 f0 = hp[0], f1 = hp[1];
            a[0] = bfbits(f0.x); a[1] = bfbits(f0.y); a[2] = bfbits(f0.z); a[3] = bfbits(f0.w);
            a[4] = bfbits(f1.x); a[5] = bfbits(f1.y); a[6] = bfbits(f1.z); a[7] = bfbits(f1.w);
        }
        // fused hb store (sector 1): 16 B, aligned (80*m + 16*quad)
        *(bf16x8*)(hb + (size_t)(m_base + li) * HROW + quad * 8) = a;
        const bf16x8 b = *(const bf16x8*)(&sm.vlr[li][0] + quad * 8);
        f32x4 acc = (f32x4){0.f, 0.f, 0.f, 0.f};
        acc = __builtin_amdgcn_mfma_f32_16x16x32_bf16(a, b, acc, 0, 0, 0);
        if (li < 8) {
#pragma unroll
            for (int i = 0; i < 4; ++i) {
                const int m = m_base + quad * 4 + i;
                if (li < 4)
                    ((__hip_bfloat16*)hb)[(size_t)m * HROW + 32 + li] = __float2bfloat16(acc[i]);
                else
                    er[m * 4 + (li - 4)] = acc[i];
            }
        }
        return;
    }
    if (blockIdx.x < NB_WGB) {
        // ---- Wc role (GRU GEMM B, unchanged values) ----
        const int idx = (blockIdx.x - NB_WC) * 1024 + t;
        const int r = idx / 160, k = idx - r * 160;
        float v = 0.f;
        if (r < 96) { if (k < 128) v = Wih[r * 128 + k]; }
        else        { if (k >= 128) v = Whh[(r - 96) * 32 + (k - 128)]; }
        Wc[idx] = __float2bfloat16(v);
        return;
    }
    // ---- Wgb role: projection B, [h*32+f][k] ----
#pragma unroll
    for (int jj = 0; jj < 4; ++jj) {
        const int id = t * 4 + jj;             // 4096 items
        const int k = id & 31, f = (id >> 5) & 31, hd = id >> 10;
        Wgb[id] = __float2bfloat16(Wg[k * 128 + hd * 32 + f]);
    }
}

// ---------------------------------------------------------------------------
// K2 (scat2): bin_buf -> dense srcs_p (ushort) + counts. Block b owns bin
// b's 256 nodes; block-OWNED 32 KB output range (no cross-XCD sharing).
// ---------------------------------------------------------------------------
__global__ __launch_bounds__(256) void k_scat2(
        const int* __restrict__ bin_cursor, const unsigned* __restrict__ bin_buf,
        unsigned short* __restrict__ srcs_p, int* __restrict__ counts) {
    __shared__ int lcnt[256];
    const int t = threadIdx.x;
    const int b = blockIdx.x;
    lcnt[t] = 0;
    __syncthreads();
    const int cb = min(bin_cursor[b * CUR_PAD], BIN_CAP);
    const uint4* bb4 = (const uint4*)(bin_buf + (size_t)b * BIN_CAP);
    for (int i = t * 4; i < cb; i += 1024) {
        const uint4 p4 = bb4[i >> 2];
#pragma unroll
        for (int k = 0; k < 4; ++k) {
            if (i + k < cb) {
                const unsigned p = (&p4.x)[k];
                const int dl = (p >> 16) & 255;
                const int pos = atomicAdd(&lcnt[dl], 1);
                if (pos < CAP)
                    srcs_p[(size_t)(b * 256 + dl) * CAP + pos] = (unsigned short)(p & 0xffff);
            }
        }
    }
    __syncthreads();
    const int node = b * 256 + t;
    if (node < N_NODES) counts[node] = lcnt[t];
}

// ---------------------------------------------------------------------------
// K3 (aggr + project + GRU). R14: LDS lifetime union — {list,lcnt,Sn}
// (dead after phase 1.5) share storage with ex (born in phase 2 after a
// __syncthreads). LDS 22016 -> ~15.4 KB => 8 blocks/CU (was 7), +14%
// resident waves for this latency-bound kernel. Phases byte-identical.
// ---------------------------------------------------------------------------
__global__ __launch_bounds__(256) void k_aggr_gru(
        const int* __restrict__ counts, const unsigned short* __restrict__ srcs_p,
        const unsigned short* __restrict__ hb,
        const float* __restrict__ er,
        const float* __restrict__ h, const __hip_bfloat16* __restrict__ Wc,
        const __hip_bfloat16* __restrict__ Wgb,
        const float* __restrict__ bih, const float* __restrict__ bhh,
        float* __restrict__ out) {
    __shared__ __hip_bfloat16 xh_tile[16][160];   // 5 KB
    __shared__ float eel_s[4][256];               // 4 KB
    __shared__ union {
        struct {
            unsigned short list[16][CAP];         // 2 KB   (phase <=1)
            int lcnt[16];                         // 64 B   (phase <=1)
            unsigned Sn[16][64];                  // 4 KB   (phase <=1.5)
        } a;
        float ex[2][3][16][16];                   // 6 KB   (phase 2)
    } u;                                          // 6.2 KB
    const int t = threadIdx.x;
    const int wave = t >> 6;
    const int lane = t & 63;
    const int mbase = blockIdx.x * 16;

    // ---- stage A': coalesced list + count load ----
    if (t < 16) u.a.lcnt[t] = min(counts[mbase + t], CAP);
    {
        const ushort4* sp = (const ushort4*)(srcs_p + (size_t)mbase * CAP);
        ((ushort4*)&u.a.list[0][0])[t] = sp[t];   // 256 x 8 B = 2 KB
    }
    __syncthreads();

    // ---- phase 1: 4 nodes per wave; weights (eel) + bf16-h gather ----
    float* eel = eel_s[wave];
    const int hs = lane & 3;
    const int eq = lane >> 4;          // edge slot within round (0..3)
    const int dw = lane & 15;          // dword index in row sector 1
    for (int uu = 0; uu < 4; ++uu) {
        const int row = wave * 4 + uu;
        const int n = mbase + row;
        const float ern = er[n * 4 + hs];
        const int cnt = u.a.lcnt[row];
        const unsigned short* sl = u.a.list[row];
        // zero eel (stale from previous node; gather reads full rounds)
        eel[lane] = 0.f; eel[64 + lane] = 0.f;
        eel[128 + lane] = 0.f; eel[192 + lane] = 0.f;
        __builtin_amdgcn_wave_barrier();
        float psum = 0.f;
#pragma unroll
        for (int p = 0; p < 4; ++p) {
            const int j = p * 64 + lane;           // j&3 == lane&3
            if (j < cnt * 4) {
                const int s = sl[j >> 2];
                const float elv = __bfloat162float(
                    *(const __hip_bfloat16*)(hb + (size_t)s * HROW + 32 + hs));
                float v = elv + ern;
                v = v > 0.f ? v : 0.2f * v;        // leaky_relu(0.2)
                const float e = __expf(v);
                eel[j] = e;
                psum += e;
            }
        }
        __builtin_amdgcn_wave_barrier();
        float a00 = 0.f, a01 = 0.f, a10 = 0.f, a11 = 0.f;
        float a20 = 0.f, a21 = 0.f, a30 = 0.f, a31 = 0.f;
        for (int i = 0; i < cnt; i += 16) {
            int e[4];
#pragma unroll
            for (int j = 0; j < 4; ++j) {
                const int ee = i + j * 4 + eq;
                e[j] = (ee < cnt) ? sl[ee] : sl[0]; // cnt>0 inside loop
            }
            unsigned q[4];
#pragma unroll
            for (int j = 0; j < 4; ++j)
                q[j] = *(const unsigned*)(hb + (size_t)e[j] * HROW + dw * 2);
#pragma unroll
            for (int j = 0; j < 4; ++j) {
                const int ee = i + j * 4 + eq;
                const float lo = __uint_as_float(q[j] << 16);
                const float hi = __uint_as_float(q[j] & 0xffff0000u);
                const float w0 = eel[ee * 4 + 0];
                const float w1 = eel[ee * 4 + 1];
                const float w2 = eel[ee * 4 + 2];
                const float w3 = eel[ee * 4 + 3];
                a00 = fmaf(w0, lo, a00); a01 = fmaf(w0, hi, a01);
                a10 = fmaf(w1, lo, a10); a11 = fmaf(w1, hi, a11);
                a20 = fmaf(w2, lo, a20); a21 = fmaf(w2, hi, a21);
                a30 = fmaf(w3, lo, a30); a31 = fmaf(w3, hi, a31);
            }
        }
        __builtin_amdgcn_wave_barrier();          // eel fully consumed
        // fold the 4 edge-slots (same dw, different eq)
#pragma unroll
        for (int m = 16; m < 64; m <<= 1) {
            a00 += __shfl_xor(a00, m, 64); a01 += __shfl_xor(a01, m, 64);
            a10 += __shfl_xor(a10, m, 64); a11 += __shfl_xor(a11, m, 64);
            a20 += __shfl_xor(a20, m, 64); a21 += __shfl_xor(a21, m, 64);
            a30 += __shfl_xor(a30, m, 64); a31 += __shfl_xor(a31, m, 64);
        }
        // psum: lane L holds head (L&3) total after masks 4..32
#pragma unroll
        for (int m = 4; m < 64; m <<= 1) psum += __shfl_xor(psum, m, 64);
        const float inv0 = (cnt > 0) ? 1.f / __shfl(psum, 0, 64) : 0.f;
        const float inv1 = (cnt > 0) ? 1.f / __shfl(psum, 1, 64) : 0.f;
        const float inv2 = (cnt > 0) ? 1.f / __shfl(psum, 2, 64) : 0.f;
        const float inv3 = (cnt > 0) ? 1.f / __shfl(psum, 3, 64) : 0.f;
        if (lane < 16) {                          // dw == lane: feats 2dw,2dw+1
            u.a.Sn[row][0 * 16 + lane] = (unsigned)bfu16(a00 * inv0) | ((unsigned)bfu16(a01 * inv0) << 16);
            u.a.Sn[row][1 * 16 + lane] = (unsigned)bfu16(a10 * inv1) | ((unsigned)bfu16(a11 * inv1) << 16);
            u.a.Sn[row][2 * 16 + lane] = (unsigned)bfu16(a20 * inv2) | ((unsigned)bfu16(a21 * inv2) << 16);
            u.a.Sn[row][3 * 16 + lane] = (unsigned)bfu16(a30 * inv3) | ((unsigned)bfu16(a31 * inv3) << 16);
        }
        if (lane < 32)
            xh_tile[row][128 + lane] = __float2bfloat16(h[(size_t)n * 32 + lane]);
    }
    __syncthreads();

    // ---- phase 1.5: projection MFMA, wave = head ----
    {
        const int li = lane & 15, quad = lane >> 4;
        const int head = wave;
        const __hip_bfloat16* snb = (const __hip_bfloat16*)&u.a.Sn[0][0]; // [16][128]
        const bf16x8 aS = *(const bf16x8*)(snb + li * 128 + head * 32 + quad * 8);
        const bf16x8 b0 = *(const bf16x8*)(Wgb + (size_t)(head * 32 + li) * 32 + quad * 8);
        const bf16x8 b1 = *(const bf16x8*)(Wgb + (size_t)(head * 32 + 16 + li) * 32 + quad * 8);
        f32x4 c0 = (f32x4){0.f, 0.f, 0.f, 0.f};
        f32x4 c1 = (f32x4){0.f, 0.f, 0.f, 0.f};
        c0 = __builtin_amdgcn_mfma_f32_16x16x32_bf16(aS, b0, c0, 0, 0, 0);
        c1 = __builtin_amdgcn_mfma_f32_16x16x32_bf16(aS, b1, c1, 0, 0, 0);
#pragma unroll
        for (int i = 0; i < 4; ++i) {
            const int row = quad * 4 + i;
            xh_tile[row][head * 32 + li]      = __float2bfloat16(c0[i]);
            xh_tile[row][head * 32 + 16 + li] = __float2bfloat16(c1[i]);
        }
    }
    __syncthreads();   // Sn dead past here; u.ex may now be written

    // ---- phase 2: GRU MFMA, 3 tiles per wave, gh exchange via LDS ----
    const int li = lane & 15, quad = lane >> 4;
    const int cb = wave >> 1;          // output col block
    const int ghrole = wave & 1;       // 0: gi tiles, 1: gh tiles
    bf16x8 a[5];
#pragma unroll
    for (int s = 0; s < 5; ++s)
        a[s] = *(const bf16x8*)((const char*)&xh_tile[0][0] + li * 320 + s * 64 + quad * 16);
    f32x4 acc[3];
#pragma unroll
    for (int g = 0; g < 3; ++g) {      // g: 0=r, 1=z, 2=n
        acc[g] = (f32x4){0.f, 0.f, 0.f, 0.f};
        const int j = g * 2 + cb + ghrole * 6;
        const bf16x8* bp = (const bf16x8*)(Wc + (size_t)(j * 16 + li) * 160 + quad * 8);
        acc[g] = __builtin_amdgcn_mfma_f32_16x16x32_bf16(a[0], bp[0],  acc[g], 0, 0, 0);
        acc[g] = __builtin_amdgcn_mfma_f32_16x16x32_bf16(a[1], bp[4],  acc[g], 0, 0, 0);
        acc[g] = __builtin_amdgcn_mfma_f32_16x16x32_bf16(a[2], bp[8],  acc[g], 0, 0, 0);
        acc[g] = __builtin_amdgcn_mfma_f32_16x16x32_bf16(a[3], bp[12], acc[g], 0, 0, 0);
        acc[g] = __builtin_amdgcn_mfma_f32_16x16x32_bf16(a[4], bp[16], acc[g], 0, 0, 0);
    }
    if (ghrole) {
#pragma unroll
        for (int g = 0; g < 3; ++g)
#pragma unroll
            for (int i = 0; i < 4; ++i)
                u.ex[cb][g][quad * 4 + i][li] = acc[g][i];
    }
    __syncthreads();
    if (!ghrole) {
        const int c = cb * 16 + li;
        const float bir = bih[c],      bhr = bhh[c];
        const float biz = bih[32 + c], bhz = bhh[32 + c];
        const float bin = bih[64 + c], bhn = bhh[64 + c];
#pragma unroll
        for (int i = 0; i < 4; ++i) {
            const int row = quad * 4 + i;
            const int m = mbase + row;
            const float gr = acc[0][i] + bir + u.ex[cb][0][row][li] + bhr;
            const float gz = acc[1][i] + biz + u.ex[cb][1][row][li] + bhz;
            const float r = 1.f / (1.f + __expf(-gr));
            const float z = 1.f / (1.f + __expf(-gz));
            const float tv = acc[2][i] + bin + r * (u.ex[cb][2][row][li] + bhn);
            const float em = __expf(-2.f * fabsf(tv));
            const float nn = copysignf((1.f - em) / (1.f + em), tv);
            const float hv = h[(size_t)m * 32 + c];
            const float hn = (1.f - z) * nn + z * hv;
            out[(size_t)m * 32 + c] = hn > 0.f ? hn : (__expf(hn) - 1.f);
        }
    }
}

extern "C" void kernel_launch(void* const* d_in, const int* in_sizes, int n_in,
                              void* d_out, int out_size, void* d_ws, size_t ws_size,
                              hipStream_t stream) {
    const float* h   = (const float*)d_in[0];
    const float* Wg  = (const float*)d_in[1];
    const float* al  = (const float*)d_in[2];
    const float* ar  = (const float*)d_in[3];
    const float* Wih = (const float*)d_in[4];
    const float* Whh = (const float*)d_in[5];
    const float* bih = (const float*)d_in[6];
    const float* bhh = (const float*)d_in[7];
    const int* src   = (const int*)d_in[8];
    const int* dst   = (const int*)d_in[9];
    float* out = (float*)d_out;

    // workspace layout (~18 MB). hb first; stray gather reads (e<65536) reach
    // at most 5.25 MB — inside bin_buf, safe.
    unsigned short* hb = (unsigned short*)d_ws;               // N*HROW ushort (4.0 MB)
    unsigned* bin_buf = (unsigned*)(hb + (size_t)N_NODES * HROW); // NBINS*BIN_CAP (6.4 MB)
    unsigned short* srcs_p = (unsigned short*)(bin_buf + (size_t)NBINS * BIN_CAP); // 6.4 MB
    int* counts = (int*)(srcs_p + (size_t)N_NODES * CAP);     // N int (200 KB)
    float* er = (float*)(counts + N_NODES);                   // N*4 f32
    __hip_bfloat16* Wc  = (__hip_bfloat16*)(er + (size_t)N_NODES * 4); // 30720 bf16
    __hip_bfloat16* Wgb = Wc + 30720;                         // 4096 bf16
    int* bin_cursor = (int*)(Wgb + 4096);                     // NBINS*CUR_PAD

    hipMemsetAsync(bin_cursor, 0, NBINS * CUR_PAD * sizeof(int), stream);
    k_part_prep<<<PREP_TOTAL, 1024, 0, stream>>>(
        src, dst, bin_cursor, bin_buf, h, Wg, al, ar, Wih, Whh,
        hb, er, Wc, Wgb);
    k_scat2<<<NBINS, 256, 0, stream>>>(bin_cursor, bin_buf, srcs_p, counts);
    k_aggr_gru<<<AGGR_BLOCKS, 256, 0, stream>>>(
        counts, srcs_p, hb, er, h, Wc, Wgb, bih, bhh, out);
}

// Round 15
// 140.177 us; speedup vs baseline: 1.0020x; 1.0020x over previous
//
#include <hip/hip_runtime.h>
#include <hip/hip_bf16.h>
#include <cmath>

#define N_NODES 50000
#define N_EDGES 800000
#define CAP 64                                /* per-node cap; Poisson(16) tail @64 ~1e-19 */

#define NBINS 196                             /* bin = dst >> 8 (256 nodes/bin) */
#define BIN_CAP 8192                          /* expected ~4096/bin */
#define CUR_PAD 32                            /* 1 cache line per bin cursor */

#define P1_EPT 16                             /* edges per thread (1024-thr blocks) */
#define P1_EPB (1024 * P1_EPT)                /* 16384 */
#define P1_BLOCKS ((N_EDGES + P1_EPB - 1) / P1_EPB)  /* 49 */

#define HROW 40                               /* hb row: 32 feat + 4 el(bf16) + 4 pad, 80 B */

#define ELR_BLOCKS 196                        /* 3125 tiles / 16 waves */
#define WC_BLOCKS 30                          /* 30720 items / 1024 */
#define NB_ELR (P1_BLOCKS)                    /* 49 */
#define NB_WC  (NB_ELR + ELR_BLOCKS)          /* 245 */
#define NB_WGB (NB_WC + WC_BLOCKS)            /* 275 */
#define PREP_TOTAL (NB_WGB + 1)               /* 276 */

#define AGGR_BLOCKS (N_NODES / 16)            /* 3125 */

typedef __attribute__((ext_vector_type(8))) short bf16x8;
typedef __attribute__((ext_vector_type(4))) float f32x4;

__device__ inline short bfbits(float x) {
    __hip_bfloat16 t = __float2bfloat16(x);
    return *reinterpret_cast<short*>(&t);
}
__device__ inline unsigned short bfu16(float x) {
    __hip_bfloat16 t = __float2bfloat16(x);
    return *reinterpret_cast<unsigned short*>(&t);
}

// ---------------------------------------------------------------------------
// K1 (fused bin-partition + prep), 1024 threads/block. Identical to R14.
// [0,49): partition (R10-proven bin pipeline).
// [49,245): elr: hb sector 1 (feats, fused A-fragment store) + el bf16
//           (sector 2) + er f32.
// [245,275): Wc (GRU GEMM B). [275]: Wgb (projection B fragments).
// ---------------------------------------------------------------------------
__global__ __launch_bounds__(1024) void k_part_prep(
        const int* __restrict__ src, const int* __restrict__ dst,
        int* __restrict__ bin_cursor, unsigned* __restrict__ bin_buf,
        const float* __restrict__ h, const float* __restrict__ Wg,
        const float* __restrict__ al, const float* __restrict__ ar,
        const float* __restrict__ Wih, const float* __restrict__ Whh,
        unsigned short* __restrict__ hb, float* __restrict__ er,
        __hip_bfloat16* __restrict__ Wc, __hip_bfloat16* __restrict__ Wgb) {
    const int t = threadIdx.x;
    __shared__ union {
        struct {
            int bcnt[256], bofs[256], cur[256], gbase[256];
            int wt4[4];
            unsigned stage[P1_EPB];           // 64 KB
        } part;                               // ~68.1 KB
        __hip_bfloat16 vlr[16][32];           // 1 KB
    } sm;

    if (blockIdx.x < P1_BLOCKS) {
        // ---- partition role (R10-proven) ----
        int* bcnt = sm.part.bcnt; int* bofs = sm.part.bofs;
        int* cur = sm.part.cur;   int* gbase = sm.part.gbase;
        int* wt4 = sm.part.wt4;   unsigned* stage = sm.part.stage;
        if (t < 256) bcnt[t] = 0;
        __syncthreads();
        int bn[P1_EPT];
        unsigned pk[P1_EPT];
        const int ebase = blockIdx.x * P1_EPB + t * P1_EPT;  // 800000%16==0
        if (ebase < N_EDGES) {
            int dd[P1_EPT], ss[P1_EPT];
#pragma unroll
            for (int q = 0; q < P1_EPT / 4; ++q) {
                *(int4*)(dd + q * 4) = *(const int4*)(dst + ebase + q * 4);
                *(int4*)(ss + q * 4) = *(const int4*)(src + ebase + q * 4);
            }
#pragma unroll
            for (int q = 0; q < P1_EPT; ++q) {
                bn[q] = dd[q] >> 8;
                pk[q] = (unsigned)ss[q] | ((unsigned)dd[q] << 16);
                atomicAdd(&bcnt[bn[q]], 1);
            }
        } else {
#pragma unroll
            for (int q = 0; q < P1_EPT; ++q) bn[q] = -1;
        }
        __syncthreads();
        int x = 0, vv = 0;
        if (t < 256) {
            vv = bcnt[t];
            x = vv;
            const int lane = t & 63;
#pragma unroll
            for (int m = 1; m < 64; m <<= 1) {
                const int y = __shfl_up(x, m, 64);
                if (lane >= m) x += y;
            }
            if (lane == 63) wt4[t >> 6] = x;
        }
        __syncthreads();
        if (t < 256) {
            const int wave4 = t >> 6;
            int wb = 0;
#pragma unroll
            for (int i = 0; i < 4; ++i) if (i < wave4) wb += wt4[i];
            const int off = wb + x - vv;
            bofs[t] = off;
            cur[t] = off;
            gbase[t] = (vv > 0) ? atomicAdd(&bin_cursor[t * CUR_PAD], vv) : 0;
        }
        __syncthreads();
        if (bn[0] >= 0) {
#pragma unroll
            for (int q = 0; q < P1_EPT; ++q)
                stage[atomicAdd(&cur[bn[q]], 1)] = pk[q];
        }
        __syncthreads();
        // coalesced cooperative flush (block-owned contiguous ranges)
        const int tot = wt4[0] + wt4[1] + wt4[2] + wt4[3];
        for (int i = t; i < tot; i += 1024) {
            const unsigned e = stage[i];
            const int b = e >> 24;                 // dst>>8 (dst<2^16)
            const int gi = gbase[b] + (i - bofs[b]);
            if (gi < BIN_CAP) bin_buf[(size_t)b * BIN_CAP + gi] = e;
        }
        return;
    }
    if (blockIdx.x < NB_WC) {
        // ---- elr role (hb fused): feats bf16 + el bf16 + er f32 ----
        if (t < 512) {
            const int col = t >> 5, k = t & 31;
            float v = 0.f;
            if (col < 8) {
                const int hd = col & 3;
                const float* a = (col < 4) ? (al + hd * 32) : (ar + hd * 32);
                const float* w = Wg + k * 128 + hd * 32;
#pragma unroll
                for (int f = 0; f < 32; ++f) v = fmaf(w[f], a[f], v);
            }
            sm.vlr[col][k] = __float2bfloat16(v);
        }
        __syncthreads();
        const int wave = t >> 6, lane = t & 63;
        const int li = lane & 15, quad = lane >> 4;
        const int mt = (blockIdx.x - NB_ELR) * 16 + wave;
        if (mt >= AGGR_BLOCKS) return;
        const int m_base = mt * 16;
        bf16x8 a;
        {
            const float4* hp = (const float4*)(h + (size_t)(m_base + li) * 32 + quad * 8);
            const float4 f0 = hp[0], f1 = hp[1];
            a[0] = bfbits(f0.x); a[1] = bfbits(f0.y); a[2] = bfbits(f0.z); a[3] = bfbits(f0.w);
            a[4] = bfbits(f1.x); a[5] = bfbits(f1.y); a[6] = bfbits(f1.z); a[7] = bfbits(f1.w);
        }
        // fused hb store (sector 1): 16 B, aligned (80*m + 16*quad)
        *(bf16x8*)(hb + (size_t)(m_base + li) * HROW + quad * 8) = a;
        const bf16x8 b = *(const bf16x8*)(&sm.vlr[li][0] + quad * 8);
        f32x4 acc = (f32x4){0.f, 0.f, 0.f, 0.f};
        acc = __builtin_amdgcn_mfma_f32_16x16x32_bf16(a, b, acc, 0, 0, 0);
        if (li < 8) {
#pragma unroll
            for (int i = 0; i < 4; ++i) {
                const int m = m_base + quad * 4 + i;
                if (li < 4)
                    ((__hip_bfloat16*)hb)[(size_t)m * HROW + 32 + li] = __float2bfloat16(acc[i]);
                else
                    er[m * 4 + (li - 4)] = acc[i];
            }
        }
        return;
    }
    if (blockIdx.x < NB_WGB) {
        // ---- Wc role (GRU GEMM B, unchanged values) ----
        const int idx = (blockIdx.x - NB_WC) * 1024 + t;
        const int r = idx / 160, k = idx - r * 160;
        float v = 0.f;
        if (r < 96) { if (k < 128) v = Wih[r * 128 + k]; }
        else        { if (k >= 128) v = Whh[(r - 96) * 32 + (k - 128)]; }
        Wc[idx] = __float2bfloat16(v);
        return;
    }
    // ---- Wgb role: projection B, [h*32+f][k] ----
#pragma unroll
    for (int jj = 0; jj < 4; ++jj) {
        const int id = t * 4 + jj;             // 4096 items
        const int k = id & 31, f = (id >> 5) & 31, hd = id >> 10;
        Wgb[id] = __float2bfloat16(Wg[k * 128 + hd * 32 + f]);
    }
}

// ---------------------------------------------------------------------------
// K2 (scat2): bin_buf -> dense srcs_p (ushort) + counts. Block b owns bin
// b's 256 nodes; block-OWNED 32 KB output range (no cross-XCD sharing).
// ---------------------------------------------------------------------------
__global__ __launch_bounds__(256) void k_scat2(
        const int* __restrict__ bin_cursor, const unsigned* __restrict__ bin_buf,
        unsigned short* __restrict__ srcs_p, int* __restrict__ counts) {
    __shared__ int lcnt[256];
    const int t = threadIdx.x;
    const int b = blockIdx.x;
    lcnt[t] = 0;
    __syncthreads();
    const int cb = min(bin_cursor[b * CUR_PAD], BIN_CAP);
    const uint4* bb4 = (const uint4*)(bin_buf + (size_t)b * BIN_CAP);
    for (int i = t * 4; i < cb; i += 1024) {
        const uint4 p4 = bb4[i >> 2];
#pragma unroll
        for (int k = 0; k < 4; ++k) {
            if (i + k < cb) {
                const unsigned p = (&p4.x)[k];
                const int dl = (p >> 16) & 255;
                const int pos = atomicAdd(&lcnt[dl], 1);
                if (pos < CAP)
                    srcs_p[(size_t)(b * 256 + dl) * CAP + pos] = (unsigned short)(p & 0xffff);
            }
        }
    }
    __syncthreads();
    const int node = b * 256 + t;
    if (node < N_NODES) counts[node] = lcnt[t];
}

// ---------------------------------------------------------------------------
// K3 (aggr + project + GRU). R15: phase 1 SPLIT-PIPELINED — phase A computes
// ALL 4 nodes' attention-weight rounds back-to-back (16 el-loads in flight,
// per-node eel buffers [4][4][256] = 16 KB, free since R14 proved occupancy
// isn't LDS-binding), ONE wave_barrier, then phase B runs the 4 gather
// rounds back-to-back. Serial chain depth per wave: ~8 -> ~2 exposed
// latencies. Fully unrolled; inv[4][4]/cnts[4] static-indexed (reg-resident).
// Phases 1.5/2 and all other kernels byte-identical to R14.
// ---------------------------------------------------------------------------
__global__ __launch_bounds__(256) void k_aggr_gru(
        const int* __restrict__ counts, const unsigned short* __restrict__ srcs_p,
        const unsigned short* __restrict__ hb,
        const float* __restrict__ er,
        const float* __restrict__ h, const __hip_bfloat16* __restrict__ Wc,
        const __hip_bfloat16* __restrict__ Wgb,
        const float* __restrict__ bih, const float* __restrict__ bhh,
        float* __restrict__ out) {
    __shared__ __hip_bfloat16 xh_tile[16][160];   // 5 KB
    __shared__ float eel_s[4][4][256];            // 16 KB: [wave][node][slot]
    __shared__ union {
        struct {
            unsigned short list[16][CAP];         // 2 KB   (phase <=1)
            int lcnt[16];                         // 64 B   (phase <=1)
            unsigned Sn[16][64];                  // 4 KB   (phase <=1.5)
        } a;
        float ex[2][3][16][16];                   // 6 KB   (phase 2)
    } u;                                          // 6.2 KB
    const int t = threadIdx.x;
    const int wave = t >> 6;
    const int lane = t & 63;
    const int mbase = blockIdx.x * 16;

    // ---- stage A': coalesced list + count load ----
    if (t < 16) u.a.lcnt[t] = min(counts[mbase + t], CAP);
    {
        const ushort4* sp = (const ushort4*)(srcs_p + (size_t)mbase * CAP);
        ((ushort4*)&u.a.list[0][0])[t] = sp[t];   // 256 x 8 B = 2 KB
    }
    __syncthreads();

    const int hs = lane & 3;
    const int eq = lane >> 4;          // edge slot within round (0..3)
    const int dw = lane & 15;          // dword index in row sector 1

    // ---- phase A: weights for ALL 4 nodes (loads overlap across nodes) ----
    int cnts[4];
    float inv[4][4];
#pragma unroll
    for (int uu = 0; uu < 4; ++uu) {
        const int row = wave * 4 + uu;
        const int n = mbase + row;
        const float ern = er[n * 4 + hs];
        const int cnt = u.a.lcnt[row];
        cnts[uu] = cnt;
        const unsigned short* sl = u.a.list[row];
        float* eel = eel_s[wave][uu];
        // zero own 4 slots (same-lane ordering vs writes below: no barrier)
        eel[lane] = 0.f; eel[64 + lane] = 0.f;
        eel[128 + lane] = 0.f; eel[192 + lane] = 0.f;
        float psum = 0.f;
#pragma unroll
        for (int p = 0; p < 4; ++p) {
            const int j = p * 64 + lane;           // j&3 == lane&3
            if (j < cnt * 4) {
                const int s = sl[j >> 2];
                const float elv = __bfloat162float(
                    *(const __hip_bfloat16*)(hb + (size_t)s * HROW + 32 + hs));
                float v = elv + ern;
                v = v > 0.f ? v : 0.2f * v;        // leaky_relu(0.2)
                const float e = __expf(v);
                eel[j] = e;
                psum += e;
            }
        }
        // psum: lane L holds head (L&3) total after masks 4..32
#pragma unroll
        for (int m = 4; m < 64; m <<= 1) psum += __shfl_xor(psum, m, 64);
        inv[uu][0] = (cnt > 0) ? 1.f / __shfl(psum, 0, 64) : 0.f;
        inv[uu][1] = (cnt > 0) ? 1.f / __shfl(psum, 1, 64) : 0.f;
        inv[uu][2] = (cnt > 0) ? 1.f / __shfl(psum, 2, 64) : 0.f;
        inv[uu][3] = (cnt > 0) ? 1.f / __shfl(psum, 3, 64) : 0.f;
    }
    __builtin_amdgcn_wave_barrier();   // all eel slices complete

    // ---- phase B: gathers for ALL 4 nodes (loads overlap across nodes) ----
#pragma unroll
    for (int uu = 0; uu < 4; ++uu) {
        const int row = wave * 4 + uu;
        const int n = mbase + row;
        const int cnt = cnts[uu];
        const unsigned short* sl = u.a.list[row];
        const float* eel = eel_s[wave][uu];
        float a00 = 0.f, a01 = 0.f, a10 = 0.f, a11 = 0.f;
        float a20 = 0.f, a21 = 0.f, a30 = 0.f, a31 = 0.f;
        for (int i = 0; i < cnt; i += 16) {
            int e[4];
#pragma unroll
            for (int j = 0; j < 4; ++j) {
                const int ee = i + j * 4 + eq;
                e[j] = (ee < cnt) ? sl[ee] : sl[0]; // cnt>0 inside loop
            }
            unsigned q[4];
#pragma unroll
            for (int j = 0; j < 4; ++j)
                q[j] = *(const unsigned*)(hb + (size_t)e[j] * HROW + dw * 2);
#pragma unroll
            for (int j = 0; j < 4; ++j) {
                const int ee = i + j * 4 + eq;
                const float lo = __uint_as_float(q[j] << 16);
                const float hi = __uint_as_float(q[j] & 0xffff0000u);
                const float w0 = eel[ee * 4 + 0];
                const float w1 = eel[ee * 4 + 1];
                const float w2 = eel[ee * 4 + 2];
                const float w3 = eel[ee * 4 + 3];
                a00 = fmaf(w0, lo, a00); a01 = fmaf(w0, hi, a01);
                a10 = fmaf(w1, lo, a10); a11 = fmaf(w1, hi, a11);
                a20 = fmaf(w2, lo, a20); a21 = fmaf(w2, hi, a21);
                a30 = fmaf(w3, lo, a30); a31 = fmaf(w3, hi, a31);
            }
        }
        // fold the 4 edge-slots (same dw, different eq)
#pragma unroll
        for (int m = 16; m < 64; m <<= 1) {
            a00 += __shfl_xor(a00, m, 64); a01 += __shfl_xor(a01, m, 64);
            a10 += __shfl_xor(a10, m, 64); a11 += __shfl_xor(a11, m, 64);
            a20 += __shfl_xor(a20, m, 64); a21 += __shfl_xor(a21, m, 64);
            a30 += __shfl_xor(a30, m, 64); a31 += __shfl_xor(a31, m, 64);
        }
        if (lane < 16) {                          // dw == lane: feats 2dw,2dw+1
            u.a.Sn[row][0 * 16 + lane] = (unsigned)bfu16(a00 * inv[uu][0]) | ((unsigned)bfu16(a01 * inv[uu][0]) << 16);
            u.a.Sn[row][1 * 16 + lane] = (unsigned)bfu16(a10 * inv[uu][1]) | ((unsigned)bfu16(a11 * inv[uu][1]) << 16);
            u.a.Sn[row][2 * 16 + lane] = (unsigned)bfu16(a20 * inv[uu][2]) | ((unsigned)bfu16(a21 * inv[uu][2]) << 16);
            u.a.Sn[row][3 * 16 + lane] = (unsigned)bfu16(a30 * inv[uu][3]) | ((unsigned)bfu16(a31 * inv[uu][3]) << 16);
        }
        if (lane < 32)
            xh_tile[row][128 + lane] = __float2bfloat16(h[(size_t)n * 32 + lane]);
    }
    __syncthreads();

    // ---- phase 1.5: projection MFMA, wave = head ----
    {
        const int li = lane & 15, quad = lane >> 4;
        const int head = wave;
        const __hip_bfloat16* snb = (const __hip_bfloat16*)&u.a.Sn[0][0]; // [16][128]
        const bf16x8 aS = *(const bf16x8*)(snb + li * 128 + head * 32 + quad * 8);
        const bf16x8 b0 = *(const bf16x8*)(Wgb + (size_t)(head * 32 + li) * 32 + quad * 8);
        const bf16x8 b1 = *(const bf16x8*)(Wgb + (size_t)(head * 32 + 16 + li) * 32 + quad * 8);
        f32x4 c0 = (f32x4){0.f, 0.f, 0.f, 0.f};
        f32x4 c1 = (f32x4){0.f, 0.f, 0.f, 0.f};
        c0 = __builtin_amdgcn_mfma_f32_16x16x32_bf16(aS, b0, c0, 0, 0, 0);
        c1 = __builtin_amdgcn_mfma_f32_16x16x32_bf16(aS, b1, c1, 0, 0, 0);
#pragma unroll
        for (int i = 0; i < 4; ++i) {
            const int row = quad * 4 + i;
            xh_tile[row][head * 32 + li]      = __float2bfloat16(c0[i]);
            xh_tile[row][head * 32 + 16 + li] = __float2bfloat16(c1[i]);
        }
    }
    __syncthreads();   // Sn dead past here; u.ex may now be written

    // ---- phase 2: GRU MFMA, 3 tiles per wave, gh exchange via LDS ----
    const int li = lane & 15, quad = lane >> 4;
    const int cb = wave >> 1;          // output col block
    const int ghrole = wave & 1;       // 0: gi tiles, 1: gh tiles
    bf16x8 a[5];
#pragma unroll
    for (int s = 0; s < 5; ++s)
        a[s] = *(const bf16x8*)((const char*)&xh_tile[0][0] + li * 320 + s * 64 + quad * 16);
    f32x4 acc[3];
#pragma unroll
    for (int g = 0; g < 3; ++g) {      // g: 0=r, 1=z, 2=n
        acc[g] = (f32x4){0.f, 0.f, 0.f, 0.f};
        const int j = g * 2 + cb + ghrole * 6;
        const bf16x8* bp = (const bf16x8*)(Wc + (size_t)(j * 16 + li) * 160 + quad * 8);
        acc[g] = __builtin_amdgcn_mfma_f32_16x16x32_bf16(a[0], bp[0],  acc[g], 0, 0, 0);
        acc[g] = __builtin_amdgcn_mfma_f32_16x16x32_bf16(a[1], bp[4],  acc[g], 0, 0, 0);
        acc[g] = __builtin_amdgcn_mfma_f32_16x16x32_bf16(a[2], bp[8],  acc[g], 0, 0, 0);
        acc[g] = __builtin_amdgcn_mfma_f32_16x16x32_bf16(a[3], bp[12], acc[g], 0, 0, 0);
        acc[g] = __builtin_amdgcn_mfma_f32_16x16x32_bf16(a[4], bp[16], acc[g], 0, 0, 0);
    }
    if (ghrole) {
#pragma unroll
        for (int g = 0; g < 3; ++g)
#pragma unroll
            for (int i = 0; i < 4; ++i)
                u.ex[cb][g][quad * 4 + i][li] = acc[g][i];
    }
    __syncthreads();
    if (!ghrole) {
        const int c = cb * 16 + li;
        const float bir = bih[c],      bhr = bhh[c];
        const float biz = bih[32 + c], bhz = bhh[32 + c];
        const float bin = bih[64 + c], bhn = bhh[64 + c];
#pragma unroll
        for (int i = 0; i < 4; ++i) {
            const int row = quad * 4 + i;
            const int m = mbase + row;
            const float gr = acc[0][i] + bir + u.ex[cb][0][row][li] + bhr;
            const float gz = acc[1][i] + biz + u.ex[cb][1][row][li] + bhz;
            const float r = 1.f / (1.f + __expf(-gr));
            const float z = 1.f / (1.f + __expf(-gz));
            const float tv = acc[2][i] + bin + r * (u.ex[cb][2][row][li] + bhn);
            const float em = __expf(-2.f * fabsf(tv));
            const float nn = copysignf((1.f - em) / (1.f + em), tv);
            const float hv = h[(size_t)m * 32 + c];
            const float hn = (1.f - z) * nn + z * hv;
            out[(size_t)m * 32 + c] = hn > 0.f ? hn : (__expf(hn) - 1.f);
        }
    }
}

extern "C" void kernel_launch(void* const* d_in, const int* in_sizes, int n_in,
                              void* d_out, int out_size, void* d_ws, size_t ws_size,
                              hipStream_t stream) {
    const float* h   = (const float*)d_in[0];
    const float* Wg  = (const float*)d_in[1];
    const float* al  = (const float*)d_in[2];
    const float* ar  = (const float*)d_in[3];
    const float* Wih = (const float*)d_in[4];
    const float* Whh = (const float*)d_in[5];
    const float* bih = (const float*)d_in[6];
    const float* bhh = (const float*)d_in[7];
    const int* src   = (const int*)d_in[8];
    const int* dst   = (const int*)d_in[9];
    float* out = (float*)d_out;

    // workspace layout (~18 MB). hb first; stray gather reads (e<65536) reach
    // at most 5.25 MB — inside bin_buf, safe.
    unsigned short* hb = (unsigned short*)d_ws;               // N*HROW ushort (4.0 MB)
    unsigned* bin_buf = (unsigned*)(hb + (size_t)N_NODES * HROW); // NBINS*BIN_CAP (6.4 MB)
    unsigned short* srcs_p = (unsigned short*)(bin_buf + (size_t)NBINS * BIN_CAP); // 6.4 MB
    int* counts = (int*)(srcs_p + (size_t)N_NODES * CAP);     // N int (200 KB)
    float* er = (float*)(counts + N_NODES);                   // N*4 f32
    __hip_bfloat16* Wc  = (__hip_bfloat16*)(er + (size_t)N_NODES * 4); // 30720 bf16
    __hip_bfloat16* Wgb = Wc + 30720;                         // 4096 bf16
    int* bin_cursor = (int*)(Wgb + 4096);                     // NBINS*CUR_PAD

    hipMemsetAsync(bin_cursor, 0, NBINS * CUR_PAD * sizeof(int), stream);
    k_part_prep<<<PREP_TOTAL, 1024, 0, stream>>>(
        src, dst, bin_cursor, bin_buf, h, Wg, al, ar, Wih, Whh,
        hb, er, Wc, Wgb);
    k_scat2<<<NBINS, 256, 0, stream>>>(bin_cursor, bin_buf, srcs_p, counts);
    k_aggr_gru<<<AGGR_BLOCKS, 256, 0, stream>>>(
        counts, srcs_p, hb, er, h, Wc, Wgb, bih, bhh, out);
}